// Round 1
// baseline (263.893 us; speedup 1.0000x reference)
//
#include <hip/hip_runtime.h>
#include <hip/hip_fp16.h>

// FNet Fourier mixing: out = Re(FFT(x, axis=1, norm="ortho")), x (8,4096,1024) fp32.
// Four-step FFT, 4096 = 64 x 64, pair-packed complex columns (z_p = x[:,2p] + i x[:,2p+1]).
// Round 4: register-resident radix-8x8 FFT64 (one LDS transpose instead of 3 LDS
// butterfly rounds), compile-time radix-8 twiddles, sincos -> 1 seed + fp32 complex
// recurrence. fp16 intermediate in d_ws (scaled 1/64). Fallback: round-2 fp32 kernels.

static constexpr int SEQ = 4096;
static constexpr int HID = 1024;

struct alignas(8) h2x2 { __half2 a, b; };   // two packed complex fp16 values

__device__ __forceinline__ int rev4_3(int r) {
    return ((r & 3) << 4) | (r & 12) | ((r >> 4) & 3);
}

// ---------------- register radix-8 machinery ----------------

// 8-point complex DFT (forward, W8 = e^{-2*pi*i/8}), natural in, natural out.
// All twiddles compile-time: +-1, +-i, c(1-+i), c = sqrt(2)/2.
__device__ __forceinline__ void fft8(float* xr, float* xi) {
    const float C = 0.70710678118654752f;
    float ar[8], ai[8];
    // stage 1 on bit-reversed pairs: (x0,x4),(x2,x6),(x1,x5),(x3,x7)
    ar[0] = xr[0] + xr[4];  ai[0] = xi[0] + xi[4];
    ar[1] = xr[0] - xr[4];  ai[1] = xi[0] - xi[4];
    ar[2] = xr[2] + xr[6];  ai[2] = xi[2] + xi[6];
    ar[3] = xr[2] - xr[6];  ai[3] = xi[2] - xi[6];
    ar[4] = xr[1] + xr[5];  ai[4] = xi[1] + xi[5];
    ar[5] = xr[1] - xr[5];  ai[5] = xi[1] - xi[5];
    ar[6] = xr[3] + xr[7];  ai[6] = xi[3] + xi[7];
    ar[7] = xr[3] - xr[7];  ai[7] = xi[3] - xi[7];
    // stage 2: twiddles 1, -i
    float br[8], bi[8];
    br[0] = ar[0] + ar[2];  bi[0] = ai[0] + ai[2];
    br[2] = ar[0] - ar[2];  bi[2] = ai[0] - ai[2];
    br[1] = ar[1] + ai[3];  bi[1] = ai[1] - ar[3];     // a1 + (-i)a3
    br[3] = ar[1] - ai[3];  bi[3] = ai[1] + ar[3];     // a1 - (-i)a3
    br[4] = ar[4] + ar[6];  bi[4] = ai[4] + ai[6];
    br[6] = ar[4] - ar[6];  bi[6] = ai[4] - ai[6];
    br[5] = ar[5] + ai[7];  bi[5] = ai[5] - ar[7];
    br[7] = ar[5] - ai[7];  bi[7] = ai[5] + ar[7];
    // stage 3: twiddles W8^k applied to b[4..7]
    const float t0r = br[4],                 t0i = bi[4];
    const float t1r = C * (br[5] + bi[5]),   t1i = C * (bi[5] - br[5]);   // W8^1 * b5
    const float t2r = bi[6],                 t2i = -br[6];                // -i * b6
    const float t3r = C * (bi[7] - br[7]),   t3i = -C * (br[7] + bi[7]);  // W8^3 * b7
    xr[0] = br[0] + t0r;  xi[0] = bi[0] + t0i;
    xr[4] = br[0] - t0r;  xi[4] = bi[0] - t0i;
    xr[1] = br[1] + t1r;  xi[1] = bi[1] + t1i;
    xr[5] = br[1] - t1r;  xi[5] = bi[1] - t1i;
    xr[2] = br[2] + t2r;  xi[2] = bi[2] + t2i;
    xr[6] = br[2] - t2r;  xi[6] = bi[2] - t2i;
    xr[3] = br[3] + t3r;  xi[3] = bi[3] + t3i;
    xr[7] = br[3] - t3r;  xi[7] = bi[3] - t3i;
}

// x[k] *= W^k for k=1..7, W = wc + i*ws (fp32 recurrence, err ~1e-6 << fp16 lsb).
__device__ __forceinline__ void twiddle_chain(float* xr, float* xi,
                                              const float wc, const float ws) {
    float cr = wc, ci = ws;
    #pragma unroll
    for (int k = 1; k < 8; ++k) {
        const float tr = xr[k] * cr - xi[k] * ci;
        xi[k] = xr[k] * ci + xi[k] * cr;
        xr[k] = tr;
        if (k < 7) {
            const float nr = cr * wc - ci * ws;
            const float ni = cr * ws + ci * wc;
            cr = nr;  ci = ni;
        }
    }
}

// ---------------- fp16-intermediate path (radix-8x8) ----------------
// u layout (unchanged): __half2 u[8][4096][512];
// u[b][64*n2+k1][p] = (1/64) W4096^{n2 k1} FFT64(z_p)[k1],  z_p[n1] over rows n2+64*n1.

// grid = 8 b * 64 n2 * 16 pc (32 pair-cols each); 256 thr; 16.5 KB LDS, 1 barrier.
__global__ __launch_bounds__(256) void fft_pass1_r8(const float* __restrict__ x,
                                                    __half2* __restrict__ u) {
    __shared__ float2 zs[2112];               // [k_l(8)][q(8)][c pitch 33]
    const int t  = threadIdx.x;
    const int pc = blockIdx.x & 15;
    const int n2 = (blockIdx.x >> 4) & 63;
    const int b  = blockIdx.x >> 10;
    const int c  = t & 31;                    // pair-column within chunk
    const int q  = t >> 5;                    // residue n1 mod 8

    const float* xb = x + (size_t)b * SEQ * HID + (size_t)(pc * 64 + 2 * c);
    float xr[8], xi[8];
    #pragma unroll
    for (int a = 0; a < 8; ++a) {             // n1 = 8a + q, row = n2 + 64*n1
        const float2 v = *(const float2*)(xb + (size_t)(n2 + 64 * (8 * a + q)) * HID);
        xr[a] = v.x;  xi[a] = v.y;
    }
    fft8(xr, xi);                             // y_q[k_l]
    {   // z_q[k_l] = y_q[k_l] * W64^{q k_l}
        float wsn, wcs;
        __sincosf(-0.09817477042468103f * (float)q, &wsn, &wcs);   // -2pi q/64
        twiddle_chain(xr, xi, wcs, wsn);
    }
    #pragma unroll
    for (int k = 0; k < 8; ++k)
        zs[(k * 8 + q) * 33 + c] = make_float2(xr[k], xi[k]);
    __syncthreads();
    #pragma unroll
    for (int r = 0; r < 8; ++r) {
        const float2 v = zs[(q * 8 + r) * 33 + c];
        xr[r] = v.x;  xi[r] = v.y;
    }
    fft8(xr, xi);                             // X[q + 8*kh] in slot kh

    // u[(64 n2 + q + 8 kh)][pc*32+c] = (1/64) W4096^{n2 (q+8kh)} X
    const float tw = -1.5339807878856412e-3f; // -2pi/4096
    float w0c, w0s, wsc, wss;
    __sincosf(tw * (float)(n2 * q), &w0s, &w0c);
    __sincosf(tw * (float)(n2 * 8), &wss, &wsc);
    const float sc = 0.015625f;
    w0c *= sc;  w0s *= sc;
    __half2* ub = u + (size_t)b * SEQ * 512 + (size_t)(64 * n2 + q) * 512 + pc * 32 + c;
    #pragma unroll
    for (int kh = 0; kh < 8; ++kh) {
        const float orr = xr[kh] * w0c - xi[kh] * w0s;
        const float oii = xr[kh] * w0s + xi[kh] * w0c;
        ub[(size_t)(8 * kh) * 512] = __floats2half2_rn(orr, oii);
        if (kh < 7) {
            const float nc = w0c * wsc - w0s * wss;
            const float ns = w0c * wss + w0s * wsc;
            w0c = nc;  w0s = ns;
        }
    }
}

// grid = 8 b * 1024: idx<992 -> paired {k1, 64-k1}, 32 chunks of 16 pairs;
// idx>=992 -> self-paired k1 in {0,32}, 16 chunks of 32 pairs. 256 thr; 17 KB LDS.
__global__ __launch_bounds__(256) void fft_pass2_r8(const __half2* __restrict__ u,
                                                    float* __restrict__ out) {
    __shared__ float2 vs[2176];
    const int t   = threadIdx.x;
    const int b   = blockIdx.x >> 10;
    const int idx = blockIdx.x & 1023;
    const __half2* ub = u   + (size_t)b * SEQ * 512;
    float*         ob = out + (size_t)b * SEQ * HID;
    const float scale = 0.5f;                 // total 1/128 = (1/64 pass1) * this
    float xr[8], xi[8];

    if (idx < 992) {
        const int k1 = 1 + (idx >> 5);        // 1..31
        const int pc = idx & 31;              // 16-pair chunk
        const int ab = t >> 7;                // 0 -> k1, 1 -> 64-k1
        const int q  = (t >> 4) & 7;          // residue n2 mod 8
        const int c  = t & 15;
        const int k1sel = ab ? 64 - k1 : k1;
        const int p  = pc * 16 + c;
        const __half2* up = ub + (size_t)k1sel * 512 + p;
        #pragma unroll
        for (int a = 0; a < 8; ++a) {         // n2 = 8a + q
            const float2 v = __half22float2(up[(size_t)(64 * (8 * a + q)) * 512]);
            xr[a] = v.x;  xi[a] = v.y;
        }
        fft8(xr, xi);
        {
            float wsn, wcs;
            __sincosf(-0.09817477042468103f * (float)q, &wsn, &wcs);
            twiddle_chain(xr, xi, wcs, wsn);
        }
        const int base = ab * 64;
        #pragma unroll
        for (int k = 0; k < 8; ++k)
            vs[(base + k * 8 + q) * 17 + c] = make_float2(xr[k], xi[k]);
        __syncthreads();
        #pragma unroll
        for (int r = 0; r < 8; ++r) {
            const float2 v = vs[(base + q * 8 + r) * 17 + c];
            xr[r] = v.x;  xi[r] = v.y;
        }
        fft8(xr, xi);                         // V_{ab}[q + 8 kh]
        __syncthreads();
        #pragma unroll
        for (int k = 0; k < 8; ++k)
            vs[(base + k * 8 + q) * 17 + c] = make_float2(xr[k], xi[k]);
        __syncthreads();
        // out row k1sel + 64*k2: own V[k2] + partner V_{1-ab}[63-k2]
        float* op = ob + (size_t)k1sel * HID + 2 * p;
        #pragma unroll
        for (int kh = 0; kh < 8; ++kh) {
            const float2 pv = vs[((64 - base) + (7 - kh) * 8 + (7 - q)) * 17 + c];
            const int k2 = q + 8 * kh;
            *(float2*)(op + (size_t)(64 * k2) * HID) =
                make_float2((xr[kh] + pv.x) * scale, (xi[kh] + pv.y) * scale);
        }
    } else {
        const int s  = idx - 992;
        const int k1 = (s >> 4) * 32;         // 0 or 32
        const int pc = s & 15;                // 32-pair chunk
        const int q  = t >> 5;
        const int c  = t & 31;
        const int p  = pc * 32 + c;
        const __half2* up = ub + (size_t)k1 * 512 + p;
        #pragma unroll
        for (int a = 0; a < 8; ++a) {
            const float2 v = __half22float2(up[(size_t)(64 * (8 * a + q)) * 512]);
            xr[a] = v.x;  xi[a] = v.y;
        }
        fft8(xr, xi);
        {
            float wsn, wcs;
            __sincosf(-0.09817477042468103f * (float)q, &wsn, &wcs);
            twiddle_chain(xr, xi, wcs, wsn);
        }
        #pragma unroll
        for (int k = 0; k < 8; ++k)
            vs[(k * 8 + q) * 33 + c] = make_float2(xr[k], xi[k]);
        __syncthreads();
        #pragma unroll
        for (int r = 0; r < 8; ++r) {
            const float2 v = vs[(q * 8 + r) * 33 + c];
            xr[r] = v.x;  xi[r] = v.y;
        }
        fft8(xr, xi);
        __syncthreads();
        #pragma unroll
        for (int k = 0; k < 8; ++k)
            vs[(k * 8 + q) * 33 + c] = make_float2(xr[k], xi[k]);
        __syncthreads();
        // partner index: k1==0 -> (64-k2)%64, k1==32 -> 63-k2
        const int q2 = (k1 == 0) ? ((8 - q) & 7) : (7 - q);
        float* op = ob + (size_t)k1 * HID + 2 * p;
        #pragma unroll
        for (int kh = 0; kh < 8; ++kh) {
            const int kh2 = (k1 == 0 && q == 0) ? ((8 - kh) & 7) : (7 - kh);
            const float2 pv = vs[(kh2 * 8 + q2) * 33 + c];
            const int k2 = q + 8 * kh;
            *(float2*)(op + (size_t)(64 * k2) * HID) =
                make_float2((xr[kh] + pv.x) * scale, (xi[kh] + pv.y) * scale);
        }
    }
}

// ---------------- fp32 in-place fallback (round-2 kernels, unchanged) ----------------

template <int MC>
__device__ __forceinline__ void fft64_lds(float* re, float* im, int off, int stride, int mbase) {
    #pragma unroll
    for (int s = 0; s < 3; ++s) {
        const int L = 1 << (2 * s);
        const float ang = -6.283185307179586f / (float)(4 * L);
        #pragma unroll
        for (int mi = 0; mi < MC; ++mi) {
            const int m  = mbase + mi;
            const int j  = m & (L - 1);
            const int i0 = ((m >> (2 * s)) << (2 * s + 2)) + j;
            const int a0 = (i0        ) * stride + off;
            const int a1 = (i0 +     L) * stride + off;
            const int a2 = (i0 + 2 * L) * stride + off;
            const int a3 = (i0 + 3 * L) * stride + off;
            const float e0x = re[a0], e0y = im[a0];
            const float e1x = re[a1], e1y = im[a1];
            const float e2x = re[a2], e2y = im[a2];
            const float e3x = re[a3], e3y = im[a3];
            float w1s, w1c;
            __sincosf(ang * (float)j, &w1s, &w1c);
            const float w2c = w1c * w1c - w1s * w1s, w2s = 2.f * w1c * w1s;
            const float w3c = w2c * w1c - w2s * w1s, w3s = w2c * w1s + w2s * w1c;
            const float t1x = e1x * w1c - e1y * w1s, t1y = e1x * w1s + e1y * w1c;
            const float t2x = e2x * w2c - e2y * w2s, t2y = e2x * w2s + e2y * w2c;
            const float t3x = e3x * w3c - e3y * w3s, t3y = e3x * w3s + e3y * w3c;
            const float a02x = e0x + t2x, a02y = e0y + t2y;
            const float s02x = e0x - t2x, s02y = e0y - t2y;
            const float a13x = t1x + t3x, a13y = t1y + t3y;
            const float s13x = t1x - t3x, s13y = t1y - t3y;
            re[a0] = a02x + a13x;  im[a0] = a02y + a13y;
            re[a1] = s02x + s13y;  im[a1] = s02y - s13x;
            re[a2] = a02x - a13x;  im[a2] = a02y - a13y;
            re[a3] = s02x - s13y;  im[a3] = s02y + s13x;
        }
        __syncthreads();
    }
}

__global__ __launch_bounds__(256) void fft_pass1(const float* __restrict__ x,
                                                 float* __restrict__ out) {
    __shared__ float sre[64 * 65];
    __shared__ float sim[64 * 65];
    const int t  = threadIdx.x;
    const int pc = blockIdx.x & 7;
    const int n2 = (blockIdx.x >> 3) & 63;
    const int b  = blockIdx.x >> 9;
    const float* xb = x   + (size_t)b * SEQ * HID + pc * 128;
    float*       ob = out + (size_t)b * SEQ * HID + pc * 128;

    const int c  = t & 31;
    const int r0 = t >> 5;
    #pragma unroll
    for (int i = 0; i < 8; ++i) {
        const int r  = r0 + 8 * i;
        const float4 f = *(const float4*)(xb + (size_t)(n2 + 64 * r) * HID + 4 * c);
        const int rr = rev4_3(r);
        sre[rr * 65 + 2 * c]     = f.x;  sim[rr * 65 + 2 * c]     = f.y;
        sre[rr * 65 + 2 * c + 1] = f.z;  sim[rr * 65 + 2 * c + 1] = f.w;
    }
    __syncthreads();

    fft64_lds<4>(sre, sim, t & 63, 65, 4 * (t >> 6));

    const float tw = -1.5339807878856412e-3f;
    #pragma unroll
    for (int i = 0; i < 8; ++i) {
        const int k1 = r0 + 8 * i;
        float ws, wc;
        __sincosf(tw * (float)(n2 * k1), &ws, &wc);
        const float ar = sre[k1 * 65 + 2 * c],     ai = sim[k1 * 65 + 2 * c];
        const float br = sre[k1 * 65 + 2 * c + 1], bi = sim[k1 * 65 + 2 * c + 1];
        float4 f;
        f.x = ar * wc - ai * ws;  f.y = ar * ws + ai * wc;
        f.z = br * wc - bi * ws;  f.w = br * ws + bi * wc;
        *(float4*)(ob + (size_t)(64 * n2 + k1) * HID + 4 * c) = f;
    }
}

__global__ __launch_bounds__(256) void fft_pass2(float* out) {
    __shared__ float lds[8448];
    const int t   = threadIdx.x;
    const int b   = blockIdx.x >> 9;
    const int idx = blockIdx.x & 511;
    float* ob = out + (size_t)b * SEQ * HID;
    const float scale = 1.0f / 128.0f;

    if (idx < 496) {
        const int k1 = 1 + (idx >> 4);
        const int pc = idx & 15;
        float* are = lds;          float* aim = lds + 2112;
        float* bre = lds + 4224;   float* bim = lds + 6336;
        const int c  = t & 15;
        const int rg = t >> 4;
        #pragma unroll
        for (int i = 0; i < 4; ++i) {
            const int n2 = rg + 16 * i;
            const int rr = rev4_3(n2);
            const float4 fa = *(const float4*)(ob + (size_t)(64 * n2 + k1)      * HID + pc * 64 + 4 * c);
            const float4 fb = *(const float4*)(ob + (size_t)(64 * n2 + 64 - k1) * HID + pc * 64 + 4 * c);
            are[rr * 33 + 2 * c]     = fa.x;  aim[rr * 33 + 2 * c]     = fa.y;
            are[rr * 33 + 2 * c + 1] = fa.z;  aim[rr * 33 + 2 * c + 1] = fa.w;
            bre[rr * 33 + 2 * c]     = fb.x;  bim[rr * 33 + 2 * c]     = fb.y;
            bre[rr * 33 + 2 * c + 1] = fb.z;  bim[rr * 33 + 2 * c + 1] = fb.w;
        }
        __syncthreads();

        const int lane = t & 63;
        float* fre = lds + 4224 * (lane >> 5);
        fft64_lds<4>(fre, fre + 2112, lane & 31, 33, 4 * (t >> 6));

        #pragma unroll
        for (int i = 0; i < 4; ++i) {
            const int k2 = rg + 16 * i;
            const int q  = 63 - k2;
            float4 f, g;
            f.x = (are[k2 * 33 + 2 * c]     + bre[q * 33 + 2 * c])     * scale;
            f.y = (aim[k2 * 33 + 2 * c]     + bim[q * 33 + 2 * c])     * scale;
            f.z = (are[k2 * 33 + 2 * c + 1] + bre[q * 33 + 2 * c + 1]) * scale;
            f.w = (aim[k2 * 33 + 2 * c + 1] + bim[q * 33 + 2 * c + 1]) * scale;
            *(float4*)(ob + (size_t)(k1 + 64 * k2)      * HID + pc * 64 + 4 * c) = f;
            g.x = (bre[k2 * 33 + 2 * c]     + are[q * 33 + 2 * c])     * scale;
            g.y = (bim[k2 * 33 + 2 * c]     + aim[q * 33 + 2 * c])     * scale;
            g.z = (bre[k2 * 33 + 2 * c + 1] + are[q * 33 + 2 * c + 1]) * scale;
            g.w = (bim[k2 * 33 + 2 * c + 1] + aim[q * 33 + 2 * c + 1]) * scale;
            *(float4*)(ob + (size_t)(64 - k1 + 64 * k2) * HID + pc * 64 + 4 * c) = g;
        }
    } else {
        const int s  = idx - 496;
        const int k1 = (s >> 3) * 32;
        const int pc = s & 7;
        float* sre = lds;
        float* sim = lds + 4160;
        const int c  = t & 31;
        const int rg = t >> 5;
        #pragma unroll
        for (int i = 0; i < 8; ++i) {
            const int n2 = rg + 8 * i;
            const int rr = rev4_3(n2);
            const float4 f = *(const float4*)(ob + (size_t)(64 * n2 + k1) * HID + pc * 128 + 4 * c);
            sre[rr * 65 + 2 * c]     = f.x;  sim[rr * 65 + 2 * c]     = f.y;
            sre[rr * 65 + 2 * c + 1] = f.z;  sim[rr * 65 + 2 * c + 1] = f.w;
        }
        __syncthreads();

        fft64_lds<4>(sre, sim, t & 63, 65, 4 * (t >> 6));

        #pragma unroll
        for (int i = 0; i < 8; ++i) {
            const int k2 = rg + 8 * i;
            const int q  = (k1 == 0) ? ((64 - k2) & 63) : (63 - k2);
            float4 f;
            f.x = (sre[k2 * 65 + 2 * c]     + sre[q * 65 + 2 * c])     * scale;
            f.y = (sim[k2 * 65 + 2 * c]     + sim[q * 65 + 2 * c])     * scale;
            f.z = (sre[k2 * 65 + 2 * c + 1] + sre[q * 65 + 2 * c + 1]) * scale;
            f.w = (sim[k2 * 65 + 2 * c + 1] + sim[q * 65 + 2 * c + 1]) * scale;
            *(float4*)(ob + (size_t)(k1 + 64 * k2) * HID + pc * 128 + 4 * c) = f;
        }
    }
}

extern "C" void kernel_launch(void* const* d_in, const int* in_sizes, int n_in,
                              void* d_out, int out_size, void* d_ws, size_t ws_size,
                              hipStream_t stream) {
    const float* x = (const float*)d_in[0];
    float* out = (float*)d_out;
    const size_t need = (size_t)8 * SEQ * 512 * sizeof(__half2);   // 64 MiB
    if (ws_size >= need) {
        __half2* u = (__half2*)d_ws;
        fft_pass1_r8<<<dim3(8 * 64 * 16), dim3(256), 0, stream>>>(x, u);
        fft_pass2_r8<<<dim3(8 * 1024), dim3(256), 0, stream>>>(u, out);
    } else {
        fft_pass1<<<dim3(8 * 64 * 8), dim3(256), 0, stream>>>(x, out);
        fft_pass2<<<dim3(8 * 512), dim3(256), 0, stream>>>(out);
    }
}

// Round 2
// 251.046 us; speedup vs baseline: 1.0512x; 1.0512x over previous
//
#include <hip/hip_runtime.h>
#include <hip/hip_fp16.h>

// FNet Fourier mixing: out = Re(FFT(x, axis=1, norm="ortho")), x (8,4096,1024) fp32.
// Four-step FFT, 4096 = 64 x 64, pair-packed complex columns (z_p = x[:,2p] + i x[:,2p+1]).
// Round 5: 512-thread blocks to double DRAM segment widths (pass1 reads 512B, writes
// 256B; pass2 reads 128B, writes 256B) -- theory: scattered small segments at large
// strides were the limiter (round-4 compute rewrite was neutral). Register radix-8x8
// FFT64 kept; fp16 intermediate in d_ws (scaled 1/64). Fallback: round-2 fp32 kernels.

static constexpr int SEQ = 4096;
static constexpr int HID = 1024;

struct alignas(8) h2x2 { __half2 a, b; };   // two packed complex fp16 values

__device__ __forceinline__ int rev4_3(int r) {
    return ((r & 3) << 4) | (r & 12) | ((r >> 4) & 3);
}

// ---------------- register radix-8 machinery ----------------

// 8-point complex DFT (forward, W8 = e^{-2*pi*i/8}), natural in, natural out.
__device__ __forceinline__ void fft8(float* xr, float* xi) {
    const float C = 0.70710678118654752f;
    float ar[8], ai[8];
    ar[0] = xr[0] + xr[4];  ai[0] = xi[0] + xi[4];
    ar[1] = xr[0] - xr[4];  ai[1] = xi[0] - xi[4];
    ar[2] = xr[2] + xr[6];  ai[2] = xi[2] + xi[6];
    ar[3] = xr[2] - xr[6];  ai[3] = xi[2] - xi[6];
    ar[4] = xr[1] + xr[5];  ai[4] = xi[1] + xi[5];
    ar[5] = xr[1] - xr[5];  ai[5] = xi[1] - xi[5];
    ar[6] = xr[3] + xr[7];  ai[6] = xi[3] + xi[7];
    ar[7] = xr[3] - xr[7];  ai[7] = xi[3] - xi[7];
    float br[8], bi[8];
    br[0] = ar[0] + ar[2];  bi[0] = ai[0] + ai[2];
    br[2] = ar[0] - ar[2];  bi[2] = ai[0] - ai[2];
    br[1] = ar[1] + ai[3];  bi[1] = ai[1] - ar[3];
    br[3] = ar[1] - ai[3];  bi[3] = ai[1] + ar[3];
    br[4] = ar[4] + ar[6];  bi[4] = ai[4] + ai[6];
    br[6] = ar[4] - ar[6];  bi[6] = ai[4] - ai[6];
    br[5] = ar[5] + ai[7];  bi[5] = ai[5] - ar[7];
    br[7] = ar[5] - ai[7];  bi[7] = ai[5] + ar[7];
    const float t0r = br[4],                 t0i = bi[4];
    const float t1r = C * (br[5] + bi[5]),   t1i = C * (bi[5] - br[5]);
    const float t2r = bi[6],                 t2i = -br[6];
    const float t3r = C * (bi[7] - br[7]),   t3i = -C * (br[7] + bi[7]);
    xr[0] = br[0] + t0r;  xi[0] = bi[0] + t0i;
    xr[4] = br[0] - t0r;  xi[4] = bi[0] - t0i;
    xr[1] = br[1] + t1r;  xi[1] = bi[1] + t1i;
    xr[5] = br[1] - t1r;  xi[5] = bi[1] - t1i;
    xr[2] = br[2] + t2r;  xi[2] = bi[2] + t2i;
    xr[6] = br[2] - t2r;  xi[6] = bi[2] - t2i;
    xr[3] = br[3] + t3r;  xi[3] = bi[3] + t3i;
    xr[7] = br[3] - t3r;  xi[7] = bi[3] - t3i;
}

// x[k] *= W^k for k=1..7, W = wc + i*ws (fp32 recurrence).
__device__ __forceinline__ void twiddle_chain(float* xr, float* xi,
                                              const float wc, const float ws) {
    float cr = wc, ci = ws;
    #pragma unroll
    for (int k = 1; k < 8; ++k) {
        const float tr = xr[k] * cr - xi[k] * ci;
        xi[k] = xr[k] * ci + xi[k] * cr;
        xr[k] = tr;
        if (k < 7) {
            const float nr = cr * wc - ci * ws;
            const float ni = cr * ws + ci * wc;
            cr = nr;  ci = ni;
        }
    }
}

// ---------------- fp16-intermediate path (radix-8x8, wide blocks) ----------------
// u layout (unchanged): __half2 u[8][4096][512];
// u[b][64*n2+k1][p] = (1/64) W4096^{n2 k1} FFT64(z_p)[k1],  z_p[n1] over rows n2+64*n1.

// grid = 8 b * 64 n2 * 8 pc (64 pair-cols each); 512 thr; 32.5 KB LDS.
// Wave = uniform q -> 512 B read segments, 256 B u-write segments.
__global__ __launch_bounds__(512, 4) void fft_pass1_w(const float* __restrict__ x,
                                                      __half2* __restrict__ u) {
    __shared__ float sre[4160];               // [k(8)][q(8)] pitch 65 over c(64)
    __shared__ float sim[4160];
    const int t  = threadIdx.x;
    const int pc = blockIdx.x & 7;
    const int n2 = (blockIdx.x >> 3) & 63;
    const int b  = blockIdx.x >> 9;
    const int c  = t & 63;                    // pair-column within chunk
    const int q  = t >> 6;                    // residue n1 mod 8 (== wave id)

    const float* xb = x + (size_t)b * SEQ * HID + (size_t)(pc * 128 + 2 * c);
    float xr[8], xi[8];
    #pragma unroll
    for (int a = 0; a < 8; ++a) {             // n1 = 8a + q, row = n2 + 64*n1
        const float2 v = *(const float2*)(xb + (size_t)(n2 + 64 * (8 * a + q)) * HID);
        xr[a] = v.x;  xi[a] = v.y;
    }
    fft8(xr, xi);
    {   float wsn, wcs;
        __sincosf(-0.09817477042468103f * (float)q, &wsn, &wcs);   // -2pi q/64
        twiddle_chain(xr, xi, wcs, wsn);
    }
    #pragma unroll
    for (int k = 0; k < 8; ++k) {
        sre[(k * 8 + q) * 65 + c] = xr[k];
        sim[(k * 8 + q) * 65 + c] = xi[k];
    }
    __syncthreads();
    #pragma unroll
    for (int r = 0; r < 8; ++r) {
        xr[r] = sre[(q * 8 + r) * 65 + c];
        xi[r] = sim[(q * 8 + r) * 65 + c];
    }
    fft8(xr, xi);                             // X[q + 8*kh] in slot kh

    const float tw = -1.5339807878856412e-3f; // -2pi/4096
    float w0c, w0s, wsc, wss;
    __sincosf(tw * (float)(n2 * q), &w0s, &w0c);
    __sincosf(tw * (float)(n2 * 8), &wss, &wsc);
    const float sc = 0.015625f;
    w0c *= sc;  w0s *= sc;
    __half2* ub = u + (size_t)b * SEQ * 512 + (size_t)(64 * n2 + q) * 512 + pc * 64 + c;
    #pragma unroll
    for (int kh = 0; kh < 8; ++kh) {
        const float orr = xr[kh] * w0c - xi[kh] * w0s;
        const float oii = xr[kh] * w0s + xi[kh] * w0c;
        ub[(size_t)(8 * kh) * 512] = __floats2half2_rn(orr, oii);
        if (kh < 7) {
            const float nc = w0c * wsc - w0s * wss;
            const float ns = w0c * wss + w0s * wsc;
            w0c = nc;  w0s = ns;
        }
    }
}

// grid = 8 b * 512: idx<496 -> paired {k1, 64-k1}, 16 chunks of 32 pairs;
// idx>=496 -> self-paired k1 in {0,32}, 8 chunks of 64 pairs. 512 thr; 33 KB LDS.
// 128 B u-reads, 256-512 B out-writes.
__global__ __launch_bounds__(512, 4) void fft_pass2_w(const __half2* __restrict__ u,
                                                      float* __restrict__ out) {
    __shared__ float sre[4224];
    __shared__ float sim[4224];
    const int t   = threadIdx.x;
    const int b   = blockIdx.x >> 9;
    const int idx = blockIdx.x & 511;
    const __half2* ub = u   + (size_t)b * SEQ * 512;
    float*         ob = out + (size_t)b * SEQ * HID;
    const float scale = 0.5f;                 // total 1/128 = (1/64 pass1) * this
    float xr[8], xi[8];

    if (idx < 496) {
        const int k1 = 1 + (idx >> 4);        // 1..31
        const int pc = idx & 15;              // 32-pair chunk
        const int ab = t >> 8;                // 0 -> k1, 1 -> 64-k1
        const int q  = (t >> 5) & 7;          // residue n2 mod 8
        const int c  = t & 31;
        const int k1sel = ab ? 64 - k1 : k1;
        const int p  = pc * 32 + c;
        const __half2* up = ub + (size_t)k1sel * 512 + p;
        #pragma unroll
        for (int a = 0; a < 8; ++a) {         // n2 = 8a + q
            const float2 v = __half22float2(up[(size_t)(64 * (8 * a + q)) * 512]);
            xr[a] = v.x;  xi[a] = v.y;
        }
        fft8(xr, xi);
        {   float wsn, wcs;
            __sincosf(-0.09817477042468103f * (float)q, &wsn, &wcs);
            twiddle_chain(xr, xi, wcs, wsn);
        }
        const int base = ab * 64;
        #pragma unroll
        for (int k = 0; k < 8; ++k) {
            sre[(base + k * 8 + q) * 33 + c] = xr[k];
            sim[(base + k * 8 + q) * 33 + c] = xi[k];
        }
        __syncthreads();
        #pragma unroll
        for (int r = 0; r < 8; ++r) {
            xr[r] = sre[(base + q * 8 + r) * 33 + c];
            xi[r] = sim[(base + q * 8 + r) * 33 + c];
        }
        fft8(xr, xi);                         // V_{ab}[q + 8 kh]
        __syncthreads();
        #pragma unroll
        for (int k = 0; k < 8; ++k) {
            sre[(base + k * 8 + q) * 33 + c] = xr[k];
            sim[(base + k * 8 + q) * 33 + c] = xi[k];
        }
        __syncthreads();
        // out row k1sel + 64*k2: own V[k2] + partner V_{1-ab}[63-k2]
        float* op = ob + (size_t)k1sel * HID + 2 * p;
        #pragma unroll
        for (int kh = 0; kh < 8; ++kh) {
            const int pi = ((64 - base) + (7 - kh) * 8 + (7 - q)) * 33 + c;
            const int k2 = q + 8 * kh;
            *(float2*)(op + (size_t)(64 * k2) * HID) =
                make_float2((xr[kh] + sre[pi]) * scale, (xi[kh] + sim[pi]) * scale);
        }
    } else {
        const int s  = idx - 496;
        const int k1 = (s >> 3) * 32;         // 0 or 32
        const int pc = s & 7;                 // 64-pair chunk
        const int q  = t >> 6;
        const int c  = t & 63;
        const int p  = pc * 64 + c;
        const __half2* up = ub + (size_t)k1 * 512 + p;
        #pragma unroll
        for (int a = 0; a < 8; ++a) {
            const float2 v = __half22float2(up[(size_t)(64 * (8 * a + q)) * 512]);
            xr[a] = v.x;  xi[a] = v.y;
        }
        fft8(xr, xi);
        {   float wsn, wcs;
            __sincosf(-0.09817477042468103f * (float)q, &wsn, &wcs);
            twiddle_chain(xr, xi, wcs, wsn);
        }
        #pragma unroll
        for (int k = 0; k < 8; ++k) {
            sre[(k * 8 + q) * 65 + c] = xr[k];
            sim[(k * 8 + q) * 65 + c] = xi[k];
        }
        __syncthreads();
        #pragma unroll
        for (int r = 0; r < 8; ++r) {
            xr[r] = sre[(q * 8 + r) * 65 + c];
            xi[r] = sim[(q * 8 + r) * 65 + c];
        }
        fft8(xr, xi);
        __syncthreads();
        #pragma unroll
        for (int k = 0; k < 8; ++k) {
            sre[(k * 8 + q) * 65 + c] = xr[k];
            sim[(k * 8 + q) * 65 + c] = xi[k];
        }
        __syncthreads();
        // partner index: k1==0 -> (64-k2)%64, k1==32 -> 63-k2
        const int q2 = (k1 == 0) ? ((8 - q) & 7) : (7 - q);
        float* op = ob + (size_t)k1 * HID + 2 * p;
        #pragma unroll
        for (int kh = 0; kh < 8; ++kh) {
            const int kh2 = (k1 == 0 && q == 0) ? ((8 - kh) & 7) : (7 - kh);
            const int pi = (kh2 * 8 + q2) * 65 + c;
            const int k2 = q + 8 * kh;
            *(float2*)(op + (size_t)(64 * k2) * HID) =
                make_float2((xr[kh] + sre[pi]) * scale, (xi[kh] + sim[pi]) * scale);
        }
    }
}

// ---------------- fp32 in-place fallback (round-2 kernels, unchanged) ----------------

template <int MC>
__device__ __forceinline__ void fft64_lds(float* re, float* im, int off, int stride, int mbase) {
    #pragma unroll
    for (int s = 0; s < 3; ++s) {
        const int L = 1 << (2 * s);
        const float ang = -6.283185307179586f / (float)(4 * L);
        #pragma unroll
        for (int mi = 0; mi < MC; ++mi) {
            const int m  = mbase + mi;
            const int j  = m & (L - 1);
            const int i0 = ((m >> (2 * s)) << (2 * s + 2)) + j;
            const int a0 = (i0        ) * stride + off;
            const int a1 = (i0 +     L) * stride + off;
            const int a2 = (i0 + 2 * L) * stride + off;
            const int a3 = (i0 + 3 * L) * stride + off;
            const float e0x = re[a0], e0y = im[a0];
            const float e1x = re[a1], e1y = im[a1];
            const float e2x = re[a2], e2y = im[a2];
            const float e3x = re[a3], e3y = im[a3];
            float w1s, w1c;
            __sincosf(ang * (float)j, &w1s, &w1c);
            const float w2c = w1c * w1c - w1s * w1s, w2s = 2.f * w1c * w1s;
            const float w3c = w2c * w1c - w2s * w1s, w3s = w2c * w1s + w2s * w1c;
            const float t1x = e1x * w1c - e1y * w1s, t1y = e1x * w1s + e1y * w1c;
            const float t2x = e2x * w2c - e2y * w2s, t2y = e2x * w2s + e2y * w2c;
            const float t3x = e3x * w3c - e3y * w3s, t3y = e3x * w3s + e3y * w3c;
            const float a02x = e0x + t2x, a02y = e0y + t2y;
            const float s02x = e0x - t2x, s02y = e0y - t2y;
            const float a13x = t1x + t3x, a13y = t1y + t3y;
            const float s13x = t1x - t3x, s13y = t1y - t3y;
            re[a0] = a02x + a13x;  im[a0] = a02y + a13y;
            re[a1] = s02x + s13y;  im[a1] = s02y - s13x;
            re[a2] = a02x - a13x;  im[a2] = a02y - a13y;
            re[a3] = s02x - s13y;  im[a3] = s02y + s13x;
        }
        __syncthreads();
    }
}

__global__ __launch_bounds__(256) void fft_pass1(const float* __restrict__ x,
                                                 float* __restrict__ out) {
    __shared__ float sre[64 * 65];
    __shared__ float sim[64 * 65];
    const int t  = threadIdx.x;
    const int pc = blockIdx.x & 7;
    const int n2 = (blockIdx.x >> 3) & 63;
    const int b  = blockIdx.x >> 9;
    const float* xb = x   + (size_t)b * SEQ * HID + pc * 128;
    float*       ob = out + (size_t)b * SEQ * HID + pc * 128;

    const int c  = t & 31;
    const int r0 = t >> 5;
    #pragma unroll
    for (int i = 0; i < 8; ++i) {
        const int r  = r0 + 8 * i;
        const float4 f = *(const float4*)(xb + (size_t)(n2 + 64 * r) * HID + 4 * c);
        const int rr = rev4_3(r);
        sre[rr * 65 + 2 * c]     = f.x;  sim[rr * 65 + 2 * c]     = f.y;
        sre[rr * 65 + 2 * c + 1] = f.z;  sim[rr * 65 + 2 * c + 1] = f.w;
    }
    __syncthreads();

    fft64_lds<4>(sre, sim, t & 63, 65, 4 * (t >> 6));

    const float tw = -1.5339807878856412e-3f;
    #pragma unroll
    for (int i = 0; i < 8; ++i) {
        const int k1 = r0 + 8 * i;
        float ws, wc;
        __sincosf(tw * (float)(n2 * k1), &ws, &wc);
        const float ar = sre[k1 * 65 + 2 * c],     ai = sim[k1 * 65 + 2 * c];
        const float br = sre[k1 * 65 + 2 * c + 1], bi = sim[k1 * 65 + 2 * c + 1];
        float4 f;
        f.x = ar * wc - ai * ws;  f.y = ar * ws + ai * wc;
        f.z = br * wc - bi * ws;  f.w = br * ws + bi * wc;
        *(float4*)(ob + (size_t)(64 * n2 + k1) * HID + 4 * c) = f;
    }
}

__global__ __launch_bounds__(256) void fft_pass2(float* out) {
    __shared__ float lds[8448];
    const int t   = threadIdx.x;
    const int b   = blockIdx.x >> 9;
    const int idx = blockIdx.x & 511;
    float* ob = out + (size_t)b * SEQ * HID;
    const float scale = 1.0f / 128.0f;

    if (idx < 496) {
        const int k1 = 1 + (idx >> 4);
        const int pc = idx & 15;
        float* are = lds;          float* aim = lds + 2112;
        float* bre = lds + 4224;   float* bim = lds + 6336;
        const int c  = t & 15;
        const int rg = t >> 4;
        #pragma unroll
        for (int i = 0; i < 4; ++i) {
            const int n2 = rg + 16 * i;
            const int rr = rev4_3(n2);
            const float4 fa = *(const float4*)(ob + (size_t)(64 * n2 + k1)      * HID + pc * 64 + 4 * c);
            const float4 fb = *(const float4*)(ob + (size_t)(64 * n2 + 64 - k1) * HID + pc * 64 + 4 * c);
            are[rr * 33 + 2 * c]     = fa.x;  aim[rr * 33 + 2 * c]     = fa.y;
            are[rr * 33 + 2 * c + 1] = fa.z;  aim[rr * 33 + 2 * c + 1] = fa.w;
            bre[rr * 33 + 2 * c]     = fb.x;  bim[rr * 33 + 2 * c]     = fb.y;
            bre[rr * 33 + 2 * c + 1] = fb.z;  bim[rr * 33 + 2 * c + 1] = fb.w;
        }
        __syncthreads();

        const int lane = t & 63;
        float* fre = lds + 4224 * (lane >> 5);
        fft64_lds<4>(fre, fre + 2112, lane & 31, 33, 4 * (t >> 6));

        #pragma unroll
        for (int i = 0; i < 4; ++i) {
            const int k2 = rg + 16 * i;
            const int q  = 63 - k2;
            float4 f, g;
            f.x = (are[k2 * 33 + 2 * c]     + bre[q * 33 + 2 * c])     * scale;
            f.y = (aim[k2 * 33 + 2 * c]     + bim[q * 33 + 2 * c])     * scale;
            f.z = (are[k2 * 33 + 2 * c + 1] + bre[q * 33 + 2 * c + 1]) * scale;
            f.w = (aim[k2 * 33 + 2 * c + 1] + bim[q * 33 + 2 * c + 1]) * scale;
            *(float4*)(ob + (size_t)(k1 + 64 * k2)      * HID + pc * 64 + 4 * c) = f;
            g.x = (bre[k2 * 33 + 2 * c]     + are[q * 33 + 2 * c])     * scale;
            g.y = (bim[k2 * 33 + 2 * c]     + aim[q * 33 + 2 * c])     * scale;
            g.z = (bre[k2 * 33 + 2 * c + 1] + are[q * 33 + 2 * c + 1]) * scale;
            g.w = (bim[k2 * 33 + 2 * c + 1] + aim[q * 33 + 2 * c + 1]) * scale;
            *(float4*)(ob + (size_t)(64 - k1 + 64 * k2) * HID + pc * 64 + 4 * c) = g;
        }
    } else {
        const int s  = idx - 496;
        const int k1 = (s >> 3) * 32;
        const int pc = s & 7;
        float* sre = lds;
        float* sim = lds + 4160;
        const int c  = t & 31;
        const int rg = t >> 5;
        #pragma unroll
        for (int i = 0; i < 8; ++i) {
            const int n2 = rg + 8 * i;
            const int rr = rev4_3(n2);
            const float4 f = *(const float4*)(ob + (size_t)(64 * n2 + k1) * HID + pc * 128 + 4 * c);
            sre[rr * 65 + 2 * c]     = f.x;  sim[rr * 65 + 2 * c]     = f.y;
            sre[rr * 65 + 2 * c + 1] = f.z;  sim[rr * 65 + 2 * c + 1] = f.w;
        }
        __syncthreads();

        fft64_lds<4>(sre, sim, t & 63, 65, 4 * (t >> 6));

        #pragma unroll
        for (int i = 0; i < 8; ++i) {
            const int k2 = rg + 8 * i;
            const int q  = (k1 == 0) ? ((64 - k2) & 63) : (63 - k2);
            float4 f;
            f.x = (sre[k2 * 65 + 2 * c]     + sre[q * 65 + 2 * c])     * scale;
            f.y = (sim[k2 * 65 + 2 * c]     + sim[q * 65 + 2 * c])     * scale;
            f.z = (sre[k2 * 65 + 2 * c + 1] + sre[q * 65 + 2 * c + 1]) * scale;
            f.w = (sim[k2 * 65 + 2 * c + 1] + sim[q * 65 + 2 * c + 1]) * scale;
            *(float4*)(ob + (size_t)(k1 + 64 * k2) * HID + pc * 128 + 4 * c) = f;
        }
    }
}

extern "C" void kernel_launch(void* const* d_in, const int* in_sizes, int n_in,
                              void* d_out, int out_size, void* d_ws, size_t ws_size,
                              hipStream_t stream) {
    const float* x = (const float*)d_in[0];
    float* out = (float*)d_out;
    const size_t need = (size_t)8 * SEQ * 512 * sizeof(__half2);   // 64 MiB
    if (ws_size >= need) {
        __half2* u = (__half2*)d_ws;
        fft_pass1_w<<<dim3(8 * 64 * 8), dim3(512), 0, stream>>>(x, u);
        fft_pass2_w<<<dim3(8 * 512), dim3(512), 0, stream>>>(u, out);
    } else {
        fft_pass1<<<dim3(8 * 64 * 8), dim3(256), 0, stream>>>(x, out);
        fft_pass2<<<dim3(8 * 512), dim3(256), 0, stream>>>(out);
    }
}

// Round 4
// 240.209 us; speedup vs baseline: 1.0986x; 1.0451x over previous
//
#include <hip/hip_runtime.h>
#include <hip/hip_fp16.h>

// FNet Fourier mixing: out = Re(FFT(x, axis=1, norm="ortho")), x (8,4096,1024) fp32.
// Four-step FFT, 4096 = 64 x 64, pair-packed complex columns (z_p = x[:,2p] + i x[:,2p+1]).
// Round 7 (= round 6 with compile fix): 2 column-pairs per thread -> all DRAM segments
// doubled again (pass1 reads 1KiB, u-writes 512B; pass2 u-reads 256-512B, out-writes
// 512B-1KiB), nontemporal hints via native ext_vector_type (HIP float4 is a class and
// rejected by __builtin_nontemporal_*). Register radix-8x8 FFT64; fp16 intermediate
// in d_ws (scaled 1/64). Fallback: round-2 fp32 kernels.

static constexpr int SEQ = 4096;
static constexpr int HID = 1024;

struct alignas(8) h2x2 { __half2 a, b; };   // two packed complex fp16 values

typedef float nv4 __attribute__((ext_vector_type(4)));   // native vec for NT builtins

__device__ __forceinline__ int rev4_3(int r) {
    return ((r & 3) << 4) | (r & 12) | ((r >> 4) & 3);
}

// ---------------- register radix-8 machinery ----------------

// 8-point complex DFT (forward, W8 = e^{-2*pi*i/8}), natural in, natural out.
__device__ __forceinline__ void fft8(float* xr, float* xi) {
    const float C = 0.70710678118654752f;
    float ar[8], ai[8];
    ar[0] = xr[0] + xr[4];  ai[0] = xi[0] + xi[4];
    ar[1] = xr[0] - xr[4];  ai[1] = xi[0] - xi[4];
    ar[2] = xr[2] + xr[6];  ai[2] = xi[2] + xi[6];
    ar[3] = xr[2] - xr[6];  ai[3] = xi[2] - xi[6];
    ar[4] = xr[1] + xr[5];  ai[4] = xi[1] + xi[5];
    ar[5] = xr[1] - xr[5];  ai[5] = xi[1] - xi[5];
    ar[6] = xr[3] + xr[7];  ai[6] = xi[3] + xi[7];
    ar[7] = xr[3] - xr[7];  ai[7] = xi[3] - xi[7];
    float br[8], bi[8];
    br[0] = ar[0] + ar[2];  bi[0] = ai[0] + ai[2];
    br[2] = ar[0] - ar[2];  bi[2] = ai[0] - ai[2];
    br[1] = ar[1] + ai[3];  bi[1] = ai[1] - ar[3];
    br[3] = ar[1] - ai[3];  bi[3] = ai[1] + ar[3];
    br[4] = ar[4] + ar[6];  bi[4] = ai[4] + ai[6];
    br[6] = ar[4] - ar[6];  bi[6] = ai[4] - ai[6];
    br[5] = ar[5] + ai[7];  bi[5] = ai[5] - ar[7];
    br[7] = ar[5] - ai[7];  bi[7] = ai[5] + ar[7];
    const float t0r = br[4],                 t0i = bi[4];
    const float t1r = C * (br[5] + bi[5]),   t1i = C * (bi[5] - br[5]);
    const float t2r = bi[6],                 t2i = -br[6];
    const float t3r = C * (bi[7] - br[7]),   t3i = -C * (br[7] + bi[7]);
    xr[0] = br[0] + t0r;  xi[0] = bi[0] + t0i;
    xr[4] = br[0] - t0r;  xi[4] = bi[0] - t0i;
    xr[1] = br[1] + t1r;  xi[1] = bi[1] + t1i;
    xr[5] = br[1] - t1r;  xi[5] = bi[1] - t1i;
    xr[2] = br[2] + t2r;  xi[2] = bi[2] + t2i;
    xr[6] = br[2] - t2r;  xi[6] = bi[2] - t2i;
    xr[3] = br[3] + t3r;  xi[3] = bi[3] + t3i;
    xr[7] = br[3] - t3r;  xi[7] = bi[3] - t3i;
}

// x[k] *= W^k for k=1..7, W = wc + i*ws (fp32 recurrence).
__device__ __forceinline__ void twiddle_chain(float* xr, float* xi,
                                              const float wc, const float ws) {
    float cr = wc, ci = ws;
    #pragma unroll
    for (int k = 1; k < 8; ++k) {
        const float tr = xr[k] * cr - xi[k] * ci;
        xi[k] = xr[k] * ci + xi[k] * cr;
        xr[k] = tr;
        if (k < 7) {
            const float nr = cr * wc - ci * ws;
            const float ni = cr * ws + ci * wc;
            cr = nr;  ci = ni;
        }
    }
}

// ---------------- fp16-intermediate path (radix-8x8, 2 col-pairs/thread) ----------------
// u layout (unchanged): __half2 u[8][4096][512];
// u[b][64*n2+k1][p] = (1/64) W4096^{n2 k1} FFT64(z_p)[k1],  z_p[n1] over rows n2+64*n1.

// grid = 8 b * 64 n2 * 4 pc (128 pair-cols each); 512 thr; ~65 KB LDS, 2 blocks/CU.
// Wave reads 1 KiB input segments, writes 512 B u segments.
__global__ __launch_bounds__(512, 4) void fft_pass1_x2(const float* __restrict__ x,
                                                       __half2* __restrict__ u) {
    __shared__ float4 zs[64 * 65];            // row = k*8+q (64), col c (64), +1 pad
    const int t  = threadIdx.x;
    const int pc = blockIdx.x & 3;
    const int n2 = (blockIdx.x >> 2) & 63;
    const int b  = blockIdx.x >> 8;
    const int c  = t & 63;                    // float4 column (2 pairs)
    const int q  = t >> 6;                    // wave id == n1 mod 8

    const float* xb = x + (size_t)b * SEQ * HID + (size_t)(pc * 256 + 4 * c);
    nv4 raw[8];
    #pragma unroll
    for (int a = 0; a < 8; ++a)               // n1 = 8a + q, row = n2 + 64*n1
        raw[a] = __builtin_nontemporal_load(
            (const nv4*)(xb + (size_t)(n2 + 64 * (8 * a + q)) * HID));

    float wq_s, wq_c;
    __sincosf(-0.09817477042468103f * (float)q, &wq_s, &wq_c);   // -2pi q/64

    float fr0[8], fi0[8], fr1[8], fi1[8];
    #pragma unroll
    for (int a = 0; a < 8; ++a) { fr0[a] = raw[a].x; fi0[a] = raw[a].y; }
    fft8(fr0, fi0);
    twiddle_chain(fr0, fi0, wq_c, wq_s);
    #pragma unroll
    for (int a = 0; a < 8; ++a) { fr1[a] = raw[a].z; fi1[a] = raw[a].w; }
    fft8(fr1, fi1);
    twiddle_chain(fr1, fi1, wq_c, wq_s);

    #pragma unroll
    for (int k = 0; k < 8; ++k)
        zs[(k * 8 + q) * 65 + c] = make_float4(fr0[k], fi0[k], fr1[k], fi1[k]);
    __syncthreads();
    float4 rw[8];
    #pragma unroll
    for (int r = 0; r < 8; ++r) rw[r] = zs[(q * 8 + r) * 65 + c];

    #pragma unroll
    for (int a = 0; a < 8; ++a) { fr0[a] = rw[a].x; fi0[a] = rw[a].y; }
    fft8(fr0, fi0);                           // X[q + 8*kh] in slot kh, col 0
    #pragma unroll
    for (int a = 0; a < 8; ++a) { fr1[a] = rw[a].z; fi1[a] = rw[a].w; }
    fft8(fr1, fi1);                           // col 1

    const float tw = -1.5339807878856412e-3f; // -2pi/4096
    float w0c, w0s, wsc, wss;
    __sincosf(tw * (float)(n2 * q), &w0s, &w0c);
    __sincosf(tw * (float)(n2 * 8), &wss, &wsc);
    const float sc = 0.015625f;
    w0c *= sc;  w0s *= sc;
    __half2* ub = u + (size_t)b * SEQ * 512 + (size_t)(64 * n2 + q) * 512 + pc * 128 + 2 * c;
    #pragma unroll
    for (int kh = 0; kh < 8; ++kh) {
        h2x2 o;
        o.a = __floats2half2_rn(fr0[kh] * w0c - fi0[kh] * w0s,
                                fr0[kh] * w0s + fi0[kh] * w0c);
        o.b = __floats2half2_rn(fr1[kh] * w0c - fi1[kh] * w0s,
                                fr1[kh] * w0s + fi1[kh] * w0c);
        *(h2x2*)(ub + (size_t)(8 * kh) * 512) = o;
        if (kh < 7) {
            const float nc = w0c * wsc - w0s * wss;
            const float ns = w0c * wss + w0s * wsc;
            w0c = nc;  w0s = ns;
        }
    }
}

// grid = 8 b * 256: idx<248 -> paired {k1, 64-k1}, 8 chunks of 64 pairs;
// idx>=248 -> self-paired k1 in {0,32}, 4 chunks of 128 pairs. 512 thr; ~66 KB LDS.
__global__ __launch_bounds__(512, 4) void fft_pass2_x2(const __half2* __restrict__ u,
                                                       float* __restrict__ out) {
    __shared__ float4 vs[128 * 33];           // paired: [slab(2)*64 rows][c(32)] +1 pad
    const int t   = threadIdx.x;
    const int b   = blockIdx.x >> 8;
    const int idx = blockIdx.x & 255;
    const __half2* ub = u   + (size_t)b * SEQ * 512;
    float*         ob = out + (size_t)b * SEQ * HID;
    const float scale = 0.5f;                 // total 1/128 = (1/64 pass1) * this
    float fr0[8], fi0[8], fr1[8], fi1[8];

    if (idx < 248) {
        const int k1 = 1 + (idx >> 3);        // 1..31
        const int pc = idx & 7;               // 64-pair chunk
        const int ab = t >> 8;                // 0 -> k1, 1 -> 64-k1
        const int q  = (t >> 5) & 7;          // residue n2 mod 8
        const int c  = t & 31;                // h2x2 column (2 pairs)
        const int k1sel = ab ? 64 - k1 : k1;
        const int p  = pc * 64 + 2 * c;       // pair index
        const __half2* up = ub + (size_t)k1sel * 512 + p;
        h2x2 raw[8];
        #pragma unroll
        for (int a = 0; a < 8; ++a)           // n2 = 8a + q
            raw[a] = *(const h2x2*)(up + (size_t)(64 * (8 * a + q)) * 512);

        float wq_s, wq_c;
        __sincosf(-0.09817477042468103f * (float)q, &wq_s, &wq_c);
        #pragma unroll
        for (int a = 0; a < 8; ++a) {
            const float2 v = __half22float2(raw[a].a);
            fr0[a] = v.x;  fi0[a] = v.y;
        }
        fft8(fr0, fi0);
        twiddle_chain(fr0, fi0, wq_c, wq_s);
        #pragma unroll
        for (int a = 0; a < 8; ++a) {
            const float2 v = __half22float2(raw[a].b);
            fr1[a] = v.x;  fi1[a] = v.y;
        }
        fft8(fr1, fi1);
        twiddle_chain(fr1, fi1, wq_c, wq_s);

        const int base = ab * 64;
        #pragma unroll
        for (int k = 0; k < 8; ++k)
            vs[(base + k * 8 + q) * 33 + c] = make_float4(fr0[k], fi0[k], fr1[k], fi1[k]);
        __syncthreads();
        float4 rw[8];
        #pragma unroll
        for (int r = 0; r < 8; ++r) rw[r] = vs[(base + q * 8 + r) * 33 + c];
        #pragma unroll
        for (int a = 0; a < 8; ++a) { fr0[a] = rw[a].x; fi0[a] = rw[a].y; }
        fft8(fr0, fi0);                       // V_ab[q + 8 kh], col 0
        #pragma unroll
        for (int a = 0; a < 8; ++a) { fr1[a] = rw[a].z; fi1[a] = rw[a].w; }
        fft8(fr1, fi1);                       // col 1
        __syncthreads();
        #pragma unroll
        for (int k = 0; k < 8; ++k)
            vs[(base + k * 8 + q) * 33 + c] = make_float4(fr0[k], fi0[k], fr1[k], fi1[k]);
        __syncthreads();

        // out row k1sel + 64*k2: own V[k2] + partner V_{1-ab}[63-k2]
        float* op = ob + (size_t)k1sel * HID + (size_t)(pc * 128 + 4 * c);
        #pragma unroll
        for (int kh = 0; kh < 8; ++kh) {
            const float4 pv = vs[((64 - base) + (7 - kh) * 8 + (7 - q)) * 33 + c];
            const int k2 = q + 8 * kh;
            nv4 o;
            o.x = (fr0[kh] + pv.x) * scale;
            o.y = (fi0[kh] + pv.y) * scale;
            o.z = (fr1[kh] + pv.z) * scale;
            o.w = (fi1[kh] + pv.w) * scale;
            __builtin_nontemporal_store(o, (nv4*)(op + (size_t)(64 * k2) * HID));
        }
    } else {
        const int s  = idx - 248;
        const int k1 = (s >> 2) * 32;         // 0 or 32
        const int pc = s & 3;                 // 128-pair chunk
        const int q  = t >> 6;
        const int c  = t & 63;                // h2x2 column (2 pairs)
        const int p  = pc * 128 + 2 * c;
        const __half2* up = ub + (size_t)k1 * 512 + p;
        h2x2 raw[8];
        #pragma unroll
        for (int a = 0; a < 8; ++a)
            raw[a] = *(const h2x2*)(up + (size_t)(64 * (8 * a + q)) * 512);

        float wq_s, wq_c;
        __sincosf(-0.09817477042468103f * (float)q, &wq_s, &wq_c);
        #pragma unroll
        for (int a = 0; a < 8; ++a) {
            const float2 v = __half22float2(raw[a].a);
            fr0[a] = v.x;  fi0[a] = v.y;
        }
        fft8(fr0, fi0);
        twiddle_chain(fr0, fi0, wq_c, wq_s);
        #pragma unroll
        for (int a = 0; a < 8; ++a) {
            const float2 v = __half22float2(raw[a].b);
            fr1[a] = v.x;  fi1[a] = v.y;
        }
        fft8(fr1, fi1);
        twiddle_chain(fr1, fi1, wq_c, wq_s);

        #pragma unroll
        for (int k = 0; k < 8; ++k)
            vs[(k * 8 + q) * 65 + c] = make_float4(fr0[k], fi0[k], fr1[k], fi1[k]);
        __syncthreads();
        float4 rw[8];
        #pragma unroll
        for (int r = 0; r < 8; ++r) rw[r] = vs[(q * 8 + r) * 65 + c];
        #pragma unroll
        for (int a = 0; a < 8; ++a) { fr0[a] = rw[a].x; fi0[a] = rw[a].y; }
        fft8(fr0, fi0);
        #pragma unroll
        for (int a = 0; a < 8; ++a) { fr1[a] = rw[a].z; fi1[a] = rw[a].w; }
        fft8(fr1, fi1);
        __syncthreads();
        #pragma unroll
        for (int k = 0; k < 8; ++k)
            vs[(k * 8 + q) * 65 + c] = make_float4(fr0[k], fi0[k], fr1[k], fi1[k]);
        __syncthreads();

        // partner index: k1==0 -> (64-k2)%64, k1==32 -> 63-k2
        const int q2 = (k1 == 0) ? ((8 - q) & 7) : (7 - q);
        float* op = ob + (size_t)k1 * HID + (size_t)(pc * 256 + 4 * c);
        #pragma unroll
        for (int kh = 0; kh < 8; ++kh) {
            const int kh2 = (k1 == 0 && q == 0) ? ((8 - kh) & 7) : (7 - kh);
            const float4 pv = vs[(kh2 * 8 + q2) * 65 + c];
            const int k2 = q + 8 * kh;
            nv4 o;
            o.x = (fr0[kh] + pv.x) * scale;
            o.y = (fi0[kh] + pv.y) * scale;
            o.z = (fr1[kh] + pv.z) * scale;
            o.w = (fi1[kh] + pv.w) * scale;
            __builtin_nontemporal_store(o, (nv4*)(op + (size_t)(64 * k2) * HID));
        }
    }
}

// ---------------- fp32 in-place fallback (round-2 kernels, unchanged) ----------------

template <int MC>
__device__ __forceinline__ void fft64_lds(float* re, float* im, int off, int stride, int mbase) {
    #pragma unroll
    for (int s = 0; s < 3; ++s) {
        const int L = 1 << (2 * s);
        const float ang = -6.283185307179586f / (float)(4 * L);
        #pragma unroll
        for (int mi = 0; mi < MC; ++mi) {
            const int m  = mbase + mi;
            const int j  = m & (L - 1);
            const int i0 = ((m >> (2 * s)) << (2 * s + 2)) + j;
            const int a0 = (i0        ) * stride + off;
            const int a1 = (i0 +     L) * stride + off;
            const int a2 = (i0 + 2 * L) * stride + off;
            const int a3 = (i0 + 3 * L) * stride + off;
            const float e0x = re[a0], e0y = im[a0];
            const float e1x = re[a1], e1y = im[a1];
            const float e2x = re[a2], e2y = im[a2];
            const float e3x = re[a3], e3y = im[a3];
            float w1s, w1c;
            __sincosf(ang * (float)j, &w1s, &w1c);
            const float w2c = w1c * w1c - w1s * w1s, w2s = 2.f * w1c * w1s;
            const float w3c = w2c * w1c - w2s * w1s, w3s = w2c * w1s + w2s * w1c;
            const float t1x = e1x * w1c - e1y * w1s, t1y = e1x * w1s + e1y * w1c;
            const float t2x = e2x * w2c - e2y * w2s, t2y = e2x * w2s + e2y * w2c;
            const float t3x = e3x * w3c - e3y * w3s, t3y = e3x * w3s + e3y * w3c;
            const float a02x = e0x + t2x, a02y = e0y + t2y;
            const float s02x = e0x - t2x, s02y = e0y - t2y;
            const float a13x = t1x + t3x, a13y = t1y + t3y;
            const float s13x = t1x - t3x, s13y = t1y - t3y;
            re[a0] = a02x + a13x;  im[a0] = a02y + a13y;
            re[a1] = s02x + s13y;  im[a1] = s02y - s13x;
            re[a2] = a02x - a13x;  im[a2] = a02y - a13y;
            re[a3] = s02x - s13y;  im[a3] = s02y + s13x;
        }
        __syncthreads();
    }
}

__global__ __launch_bounds__(256) void fft_pass1(const float* __restrict__ x,
                                                 float* __restrict__ out) {
    __shared__ float sre[64 * 65];
    __shared__ float sim[64 * 65];
    const int t  = threadIdx.x;
    const int pc = blockIdx.x & 7;
    const int n2 = (blockIdx.x >> 3) & 63;
    const int b  = blockIdx.x >> 9;
    const float* xb = x   + (size_t)b * SEQ * HID + pc * 128;
    float*       ob = out + (size_t)b * SEQ * HID + pc * 128;

    const int c  = t & 31;
    const int r0 = t >> 5;
    #pragma unroll
    for (int i = 0; i < 8; ++i) {
        const int r  = r0 + 8 * i;
        const float4 f = *(const float4*)(xb + (size_t)(n2 + 64 * r) * HID + 4 * c);
        const int rr = rev4_3(r);
        sre[rr * 65 + 2 * c]     = f.x;  sim[rr * 65 + 2 * c]     = f.y;
        sre[rr * 65 + 2 * c + 1] = f.z;  sim[rr * 65 + 2 * c + 1] = f.w;
    }
    __syncthreads();

    fft64_lds<4>(sre, sim, t & 63, 65, 4 * (t >> 6));

    const float tw = -1.5339807878856412e-3f;
    #pragma unroll
    for (int i = 0; i < 8; ++i) {
        const int k1 = r0 + 8 * i;
        float ws, wc;
        __sincosf(tw * (float)(n2 * k1), &ws, &wc);
        const float ar = sre[k1 * 65 + 2 * c],     ai = sim[k1 * 65 + 2 * c];
        const float br = sre[k1 * 65 + 2 * c + 1], bi = sim[k1 * 65 + 2 * c + 1];
        float4 f;
        f.x = ar * wc - ai * ws;  f.y = ar * ws + ai * wc;
        f.z = br * wc - bi * ws;  f.w = br * ws + bi * wc;
        *(float4*)(ob + (size_t)(64 * n2 + k1) * HID + 4 * c) = f;
    }
}

__global__ __launch_bounds__(256) void fft_pass2(float* out) {
    __shared__ float lds[8448];
    const int t   = threadIdx.x;
    const int b   = blockIdx.x >> 9;
    const int idx = blockIdx.x & 511;
    float* ob = out + (size_t)b * SEQ * HID;
    const float scale = 1.0f / 128.0f;

    if (idx < 496) {
        const int k1 = 1 + (idx >> 4);
        const int pc = idx & 15;
        float* are = lds;          float* aim = lds + 2112;
        float* bre = lds + 4224;   float* bim = lds + 6336;
        const int c  = t & 15;
        const int rg = t >> 4;
        #pragma unroll
        for (int i = 0; i < 4; ++i) {
            const int n2 = rg + 16 * i;
            const int rr = rev4_3(n2);
            const float4 fa = *(const float4*)(ob + (size_t)(64 * n2 + k1)      * HID + pc * 64 + 4 * c);
            const float4 fb = *(const float4*)(ob + (size_t)(64 * n2 + 64 - k1) * HID + pc * 64 + 4 * c);
            are[rr * 33 + 2 * c]     = fa.x;  aim[rr * 33 + 2 * c]     = fa.y;
            are[rr * 33 + 2 * c + 1] = fa.z;  aim[rr * 33 + 2 * c + 1] = fa.w;
            bre[rr * 33 + 2 * c]     = fb.x;  bim[rr * 33 + 2 * c]     = fb.y;
            bre[rr * 33 + 2 * c + 1] = fb.z;  bim[rr * 33 + 2 * c + 1] = fb.w;
        }
        __syncthreads();

        const int lane = t & 63;
        float* fre = lds + 4224 * (lane >> 5);
        fft64_lds<4>(fre, fre + 2112, lane & 31, 33, 4 * (t >> 6));

        #pragma unroll
        for (int i = 0; i < 4; ++i) {
            const int k2 = rg + 16 * i;
            const int q  = 63 - k2;
            float4 f, g;
            f.x = (are[k2 * 33 + 2 * c]     + bre[q * 33 + 2 * c])     * scale;
            f.y = (aim[k2 * 33 + 2 * c]     + bim[q * 33 + 2 * c])     * scale;
            f.z = (are[k2 * 33 + 2 * c + 1] + bre[q * 33 + 2 * c + 1]) * scale;
            f.w = (aim[k2 * 33 + 2 * c + 1] + bim[q * 33 + 2 * c + 1]) * scale;
            *(float4*)(ob + (size_t)(k1 + 64 * k2)      * HID + pc * 64 + 4 * c) = f;
            g.x = (bre[k2 * 33 + 2 * c]     + are[q * 33 + 2 * c])     * scale;
            g.y = (bim[k2 * 33 + 2 * c]     + aim[q * 33 + 2 * c])     * scale;
            g.z = (bre[k2 * 33 + 2 * c + 1] + are[q * 33 + 2 * c + 1]) * scale;
            g.w = (bim[k2 * 33 + 2 * c + 1] + aim[q * 33 + 2 * c + 1]) * scale;
            *(float4*)(ob + (size_t)(64 - k1 + 64 * k2) * HID + pc * 64 + 4 * c) = g;
        }
    } else {
        const int s  = idx - 496;
        const int k1 = (s >> 3) * 32;
        const int pc = s & 7;
        float* sre = lds;
        float* sim = lds + 4160;
        const int c  = t & 31;
        const int rg = t >> 5;
        #pragma unroll
        for (int i = 0; i < 8; ++i) {
            const int n2 = rg + 8 * i;
            const int rr = rev4_3(n2);
            const float4 f = *(const float4*)(ob + (size_t)(64 * n2 + k1) * HID + pc * 128 + 4 * c);
            sre[rr * 65 + 2 * c]     = f.x;  sim[rr * 65 + 2 * c]     = f.y;
            sre[rr * 65 + 2 * c + 1] = f.z;  sim[rr * 65 + 2 * c + 1] = f.w;
        }
        __syncthreads();

        fft64_lds<4>(sre, sim, t & 63, 65, 4 * (t >> 6));

        #pragma unroll
        for (int i = 0; i < 8; ++i) {
            const int k2 = rg + 8 * i;
            const int q  = (k1 == 0) ? ((64 - k2) & 63) : (63 - k2);
            float4 f;
            f.x = (sre[k2 * 65 + 2 * c]     + sre[q * 65 + 2 * c])     * scale;
            f.y = (sim[k2 * 65 + 2 * c]     + sim[q * 65 + 2 * c])     * scale;
            f.z = (sre[k2 * 65 + 2 * c + 1] + sre[q * 65 + 2 * c + 1]) * scale;
            f.w = (sim[k2 * 65 + 2 * c + 1] + sim[q * 65 + 2 * c + 1]) * scale;
            *(float4*)(ob + (size_t)(k1 + 64 * k2) * HID + pc * 128 + 4 * c) = f;
        }
    }
}

extern "C" void kernel_launch(void* const* d_in, const int* in_sizes, int n_in,
                              void* d_out, int out_size, void* d_ws, size_t ws_size,
                              hipStream_t stream) {
    const float* x = (const float*)d_in[0];
    float* out = (float*)d_out;
    const size_t need = (size_t)8 * SEQ * 512 * sizeof(__half2);   // 64 MiB
    if (ws_size >= need) {
        __half2* u = (__half2*)d_ws;
        fft_pass1_x2<<<dim3(8 * 64 * 4), dim3(512), 0, stream>>>(x, u);
        fft_pass2_x2<<<dim3(8 * 256), dim3(512), 0, stream>>>(u, out);
    } else {
        fft_pass1<<<dim3(8 * 64 * 8), dim3(256), 0, stream>>>(x, out);
        fft_pass2<<<dim3(8 * 512), dim3(256), 0, stream>>>(out);
    }
}

// Round 5
// 239.847 us; speedup vs baseline: 1.1003x; 1.0015x over previous
//
#include <hip/hip_runtime.h>
#include <hip/hip_fp16.h>

// FNet Fourier mixing: out = Re(FFT(x, axis=1, norm="ortho")), x (8,4096,1024) fp32.
// Four-step FFT, 4096 = 64 x 64, pair-packed complex columns (z_p = x[:,2p] + i x[:,2p+1]).
// Round 8: u layout flipped to k1-major u[b][64*k1+n2][p] so pass2 reads one contiguous
// 128KiB slab per k1 (256-512B segments at 2-16KiB stride) instead of 256B @128KiB jumps.
// Pass1 writes keep 512B wave-contiguous segments (stride grows, write-buffered).
// 2 col-pairs/thread; NT hints on once-read input / once-written output.
// Register radix-8x8 FFT64; fp16 intermediate in d_ws (scaled 1/64).
// Fallback: round-2 fp32 kernels.

static constexpr int SEQ = 4096;
static constexpr int HID = 1024;

struct alignas(8) h2x2 { __half2 a, b; };   // two packed complex fp16 values

typedef float nv4 __attribute__((ext_vector_type(4)));   // native vec for NT builtins

__device__ __forceinline__ int rev4_3(int r) {
    return ((r & 3) << 4) | (r & 12) | ((r >> 4) & 3);
}

// ---------------- register radix-8 machinery ----------------

// 8-point complex DFT (forward, W8 = e^{-2*pi*i/8}), natural in, natural out.
__device__ __forceinline__ void fft8(float* xr, float* xi) {
    const float C = 0.70710678118654752f;
    float ar[8], ai[8];
    ar[0] = xr[0] + xr[4];  ai[0] = xi[0] + xi[4];
    ar[1] = xr[0] - xr[4];  ai[1] = xi[0] - xi[4];
    ar[2] = xr[2] + xr[6];  ai[2] = xi[2] + xi[6];
    ar[3] = xr[2] - xr[6];  ai[3] = xi[2] - xi[6];
    ar[4] = xr[1] + xr[5];  ai[4] = xi[1] + xi[5];
    ar[5] = xr[1] - xr[5];  ai[5] = xi[1] - xi[5];
    ar[6] = xr[3] + xr[7];  ai[6] = xi[3] + xi[7];
    ar[7] = xr[3] - xr[7];  ai[7] = xi[3] - xi[7];
    float br[8], bi[8];
    br[0] = ar[0] + ar[2];  bi[0] = ai[0] + ai[2];
    br[2] = ar[0] - ar[2];  bi[2] = ai[0] - ai[2];
    br[1] = ar[1] + ai[3];  bi[1] = ai[1] - ar[3];
    br[3] = ar[1] - ai[3];  bi[3] = ai[1] + ar[3];
    br[4] = ar[4] + ar[6];  bi[4] = ai[4] + ai[6];
    br[6] = ar[4] - ar[6];  bi[6] = ai[4] - ai[6];
    br[5] = ar[5] + ai[7];  bi[5] = ai[5] - ar[7];
    br[7] = ar[5] - ai[7];  bi[7] = ai[5] + ar[7];
    const float t0r = br[4],                 t0i = bi[4];
    const float t1r = C * (br[5] + bi[5]),   t1i = C * (bi[5] - br[5]);
    const float t2r = bi[6],                 t2i = -br[6];
    const float t3r = C * (bi[7] - br[7]),   t3i = -C * (br[7] + bi[7]);
    xr[0] = br[0] + t0r;  xi[0] = bi[0] + t0i;
    xr[4] = br[0] - t0r;  xi[4] = bi[0] - t0i;
    xr[1] = br[1] + t1r;  xi[1] = bi[1] + t1i;
    xr[5] = br[1] - t1r;  xi[5] = bi[1] - t1i;
    xr[2] = br[2] + t2r;  xi[2] = bi[2] + t2i;
    xr[6] = br[2] - t2r;  xi[6] = bi[2] - t2i;
    xr[3] = br[3] + t3r;  xi[3] = bi[3] + t3i;
    xr[7] = br[3] - t3r;  xi[7] = bi[3] - t3i;
}

// x[k] *= W^k for k=1..7, W = wc + i*ws (fp32 recurrence).
__device__ __forceinline__ void twiddle_chain(float* xr, float* xi,
                                              const float wc, const float ws) {
    float cr = wc, ci = ws;
    #pragma unroll
    for (int k = 1; k < 8; ++k) {
        const float tr = xr[k] * cr - xi[k] * ci;
        xi[k] = xr[k] * ci + xi[k] * cr;
        xr[k] = tr;
        if (k < 7) {
            const float nr = cr * wc - ci * ws;
            const float ni = cr * ws + ci * wc;
            cr = nr;  ci = ni;
        }
    }
}

// ---------------- fp16-intermediate path (radix-8x8, 2 col-pairs/thread) ----------------
// u layout (k1-major): __half2 u[8][4096][512];
// u[b][64*k1+n2][p] = (1/64) W4096^{n2 k1} FFT64(z_p)[k1],  z_p[n1] over rows n2+64*n1.

// grid = 8 b * 64 n2 * 4 pc (128 pair-cols each); 512 thr; ~65 KB LDS, 2 blocks/CU.
// Wave reads 1 KiB input segments, writes 512 B u segments.
__global__ __launch_bounds__(512, 4) void fft_pass1_x2(const float* __restrict__ x,
                                                       __half2* __restrict__ u) {
    __shared__ float4 zs[64 * 65];            // row = k*8+q (64), col c (64), +1 pad
    const int t  = threadIdx.x;
    const int pc = blockIdx.x & 3;
    const int n2 = (blockIdx.x >> 2) & 63;
    const int b  = blockIdx.x >> 8;
    const int c  = t & 63;                    // float4 column (2 pairs)
    const int q  = t >> 6;                    // wave id == n1 mod 8

    const float* xb = x + (size_t)b * SEQ * HID + (size_t)(pc * 256 + 4 * c);
    nv4 raw[8];
    #pragma unroll
    for (int a = 0; a < 8; ++a)               // n1 = 8a + q, row = n2 + 64*n1
        raw[a] = __builtin_nontemporal_load(
            (const nv4*)(xb + (size_t)(n2 + 64 * (8 * a + q)) * HID));

    float wq_s, wq_c;
    __sincosf(-0.09817477042468103f * (float)q, &wq_s, &wq_c);   // -2pi q/64

    float fr0[8], fi0[8], fr1[8], fi1[8];
    #pragma unroll
    for (int a = 0; a < 8; ++a) { fr0[a] = raw[a].x; fi0[a] = raw[a].y; }
    fft8(fr0, fi0);
    twiddle_chain(fr0, fi0, wq_c, wq_s);
    #pragma unroll
    for (int a = 0; a < 8; ++a) { fr1[a] = raw[a].z; fi1[a] = raw[a].w; }
    fft8(fr1, fi1);
    twiddle_chain(fr1, fi1, wq_c, wq_s);

    #pragma unroll
    for (int k = 0; k < 8; ++k)
        zs[(k * 8 + q) * 65 + c] = make_float4(fr0[k], fi0[k], fr1[k], fi1[k]);
    __syncthreads();
    float4 rw[8];
    #pragma unroll
    for (int r = 0; r < 8; ++r) rw[r] = zs[(q * 8 + r) * 65 + c];

    #pragma unroll
    for (int a = 0; a < 8; ++a) { fr0[a] = rw[a].x; fi0[a] = rw[a].y; }
    fft8(fr0, fi0);                           // X[q + 8*kh] in slot kh, col 0
    #pragma unroll
    for (int a = 0; a < 8; ++a) { fr1[a] = rw[a].z; fi1[a] = rw[a].w; }
    fft8(fr1, fi1);                           // col 1

    const float tw = -1.5339807878856412e-3f; // -2pi/4096
    float w0c, w0s, wsc, wss;
    __sincosf(tw * (float)(n2 * q), &w0s, &w0c);
    __sincosf(tw * (float)(n2 * 8), &wss, &wsc);
    const float sc = 0.015625f;
    w0c *= sc;  w0s *= sc;
    // k1-major: row = 64*k1 + n2, k1 = q + 8*kh -> base row 64*q + n2, +512 rows per kh
    __half2* ub = u + (size_t)b * SEQ * 512 + (size_t)(64 * q + n2) * 512 + pc * 128 + 2 * c;
    #pragma unroll
    for (int kh = 0; kh < 8; ++kh) {
        h2x2 o;
        o.a = __floats2half2_rn(fr0[kh] * w0c - fi0[kh] * w0s,
                                fr0[kh] * w0s + fi0[kh] * w0c);
        o.b = __floats2half2_rn(fr1[kh] * w0c - fi1[kh] * w0s,
                                fr1[kh] * w0s + fi1[kh] * w0c);
        *(h2x2*)(ub + (size_t)kh * (512 * 512)) = o;
        if (kh < 7) {
            const float nc = w0c * wsc - w0s * wss;
            const float ns = w0c * wss + w0s * wsc;
            w0c = nc;  w0s = ns;
        }
    }
}

// grid = 8 b * 256: idx<248 -> paired {k1, 64-k1}, 8 chunks of 64 pairs;
// idx>=248 -> self-paired k1 in {0,32}, 4 chunks of 128 pairs. 512 thr; ~66 KB LDS.
// u-reads now walk one contiguous 128KiB slab per k1.
__global__ __launch_bounds__(512, 4) void fft_pass2_x2(const __half2* __restrict__ u,
                                                       float* __restrict__ out) {
    __shared__ float4 vs[128 * 33];           // paired: [slab(2)*64 rows][c(32)] +1 pad
    const int t   = threadIdx.x;
    const int b   = blockIdx.x >> 8;
    const int idx = blockIdx.x & 255;
    const __half2* ub = u   + (size_t)b * SEQ * 512;
    float*         ob = out + (size_t)b * SEQ * HID;
    const float scale = 0.5f;                 // total 1/128 = (1/64 pass1) * this
    float fr0[8], fi0[8], fr1[8], fi1[8];

    if (idx < 248) {
        const int k1 = 1 + (idx >> 3);        // 1..31
        const int pc = idx & 7;               // 64-pair chunk
        const int ab = t >> 8;                // 0 -> k1, 1 -> 64-k1
        const int q  = (t >> 5) & 7;          // residue n2 mod 8
        const int c  = t & 31;                // h2x2 column (2 pairs)
        const int k1sel = ab ? 64 - k1 : k1;
        const int p  = pc * 64 + 2 * c;       // pair index
        // k1-major: rows 64*k1sel + (8a+q) -- contiguous slab
        const __half2* up = ub + (size_t)(64 * k1sel) * 512 + p;
        h2x2 raw[8];
        #pragma unroll
        for (int a = 0; a < 8; ++a)           // n2 = 8a + q
            raw[a] = *(const h2x2*)(up + (size_t)(8 * a + q) * 512);

        float wq_s, wq_c;
        __sincosf(-0.09817477042468103f * (float)q, &wq_s, &wq_c);
        #pragma unroll
        for (int a = 0; a < 8; ++a) {
            const float2 v = __half22float2(raw[a].a);
            fr0[a] = v.x;  fi0[a] = v.y;
        }
        fft8(fr0, fi0);
        twiddle_chain(fr0, fi0, wq_c, wq_s);
        #pragma unroll
        for (int a = 0; a < 8; ++a) {
            const float2 v = __half22float2(raw[a].b);
            fr1[a] = v.x;  fi1[a] = v.y;
        }
        fft8(fr1, fi1);
        twiddle_chain(fr1, fi1, wq_c, wq_s);

        const int base = ab * 64;
        #pragma unroll
        for (int k = 0; k < 8; ++k)
            vs[(base + k * 8 + q) * 33 + c] = make_float4(fr0[k], fi0[k], fr1[k], fi1[k]);
        __syncthreads();
        float4 rw[8];
        #pragma unroll
        for (int r = 0; r < 8; ++r) rw[r] = vs[(base + q * 8 + r) * 33 + c];
        #pragma unroll
        for (int a = 0; a < 8; ++a) { fr0[a] = rw[a].x; fi0[a] = rw[a].y; }
        fft8(fr0, fi0);                       // V_ab[q + 8 kh], col 0
        #pragma unroll
        for (int a = 0; a < 8; ++a) { fr1[a] = rw[a].z; fi1[a] = rw[a].w; }
        fft8(fr1, fi1);                       // col 1
        __syncthreads();
        #pragma unroll
        for (int k = 0; k < 8; ++k)
            vs[(base + k * 8 + q) * 33 + c] = make_float4(fr0[k], fi0[k], fr1[k], fi1[k]);
        __syncthreads();

        // out row k1sel + 64*k2: own V[k2] + partner V_{1-ab}[63-k2]
        float* op = ob + (size_t)k1sel * HID + (size_t)(pc * 128 + 4 * c);
        #pragma unroll
        for (int kh = 0; kh < 8; ++kh) {
            const float4 pv = vs[((64 - base) + (7 - kh) * 8 + (7 - q)) * 33 + c];
            const int k2 = q + 8 * kh;
            nv4 o;
            o.x = (fr0[kh] + pv.x) * scale;
            o.y = (fi0[kh] + pv.y) * scale;
            o.z = (fr1[kh] + pv.z) * scale;
            o.w = (fi1[kh] + pv.w) * scale;
            __builtin_nontemporal_store(o, (nv4*)(op + (size_t)(64 * k2) * HID));
        }
    } else {
        const int s  = idx - 248;
        const int k1 = (s >> 2) * 32;         // 0 or 32
        const int pc = s & 3;                 // 128-pair chunk
        const int q  = t >> 6;
        const int c  = t & 63;                // h2x2 column (2 pairs)
        const int p  = pc * 128 + 2 * c;
        // k1-major slab
        const __half2* up = ub + (size_t)(64 * k1) * 512 + p;
        h2x2 raw[8];
        #pragma unroll
        for (int a = 0; a < 8; ++a)
            raw[a] = *(const h2x2*)(up + (size_t)(8 * a + q) * 512);

        float wq_s, wq_c;
        __sincosf(-0.09817477042468103f * (float)q, &wq_s, &wq_c);
        #pragma unroll
        for (int a = 0; a < 8; ++a) {
            const float2 v = __half22float2(raw[a].a);
            fr0[a] = v.x;  fi0[a] = v.y;
        }
        fft8(fr0, fi0);
        twiddle_chain(fr0, fi0, wq_c, wq_s);
        #pragma unroll
        for (int a = 0; a < 8; ++a) {
            const float2 v = __half22float2(raw[a].b);
            fr1[a] = v.x;  fi1[a] = v.y;
        }
        fft8(fr1, fi1);
        twiddle_chain(fr1, fi1, wq_c, wq_s);

        #pragma unroll
        for (int k = 0; k < 8; ++k)
            vs[(k * 8 + q) * 65 + c] = make_float4(fr0[k], fi0[k], fr1[k], fi1[k]);
        __syncthreads();
        float4 rw[8];
        #pragma unroll
        for (int r = 0; r < 8; ++r) rw[r] = vs[(q * 8 + r) * 65 + c];
        #pragma unroll
        for (int a = 0; a < 8; ++a) { fr0[a] = rw[a].x; fi0[a] = rw[a].y; }
        fft8(fr0, fi0);
        #pragma unroll
        for (int a = 0; a < 8; ++a) { fr1[a] = rw[a].z; fi1[a] = rw[a].w; }
        fft8(fr1, fi1);
        __syncthreads();
        #pragma unroll
        for (int k = 0; k < 8; ++k)
            vs[(k * 8 + q) * 65 + c] = make_float4(fr0[k], fi0[k], fr1[k], fi1[k]);
        __syncthreads();

        // partner index: k1==0 -> (64-k2)%64, k1==32 -> 63-k2
        const int q2 = (k1 == 0) ? ((8 - q) & 7) : (7 - q);
        float* op = ob + (size_t)k1 * HID + (size_t)(pc * 256 + 4 * c);
        #pragma unroll
        for (int kh = 0; kh < 8; ++kh) {
            const int kh2 = (k1 == 0 && q == 0) ? ((8 - kh) & 7) : (7 - kh);
            const float4 pv = vs[(kh2 * 8 + q2) * 65 + c];
            const int k2 = q + 8 * kh;
            nv4 o;
            o.x = (fr0[kh] + pv.x) * scale;
            o.y = (fi0[kh] + pv.y) * scale;
            o.z = (fr1[kh] + pv.z) * scale;
            o.w = (fi1[kh] + pv.w) * scale;
            __builtin_nontemporal_store(o, (nv4*)(op + (size_t)(64 * k2) * HID));
        }
    }
}

// ---------------- fp32 in-place fallback (round-2 kernels, unchanged) ----------------

template <int MC>
__device__ __forceinline__ void fft64_lds(float* re, float* im, int off, int stride, int mbase) {
    #pragma unroll
    for (int s = 0; s < 3; ++s) {
        const int L = 1 << (2 * s);
        const float ang = -6.283185307179586f / (float)(4 * L);
        #pragma unroll
        for (int mi = 0; mi < MC; ++mi) {
            const int m  = mbase + mi;
            const int j  = m & (L - 1);
            const int i0 = ((m >> (2 * s)) << (2 * s + 2)) + j;
            const int a0 = (i0        ) * stride + off;
            const int a1 = (i0 +     L) * stride + off;
            const int a2 = (i0 + 2 * L) * stride + off;
            const int a3 = (i0 + 3 * L) * stride + off;
            const float e0x = re[a0], e0y = im[a0];
            const float e1x = re[a1], e1y = im[a1];
            const float e2x = re[a2], e2y = im[a2];
            const float e3x = re[a3], e3y = im[a3];
            float w1s, w1c;
            __sincosf(ang * (float)j, &w1s, &w1c);
            const float w2c = w1c * w1c - w1s * w1s, w2s = 2.f * w1c * w1s;
            const float w3c = w2c * w1c - w2s * w1s, w3s = w2c * w1s + w2s * w1c;
            const float t1x = e1x * w1c - e1y * w1s, t1y = e1x * w1s + e1y * w1c;
            const float t2x = e2x * w2c - e2y * w2s, t2y = e2x * w2s + e2y * w2c;
            const float t3x = e3x * w3c - e3y * w3s, t3y = e3x * w3s + e3y * w3c;
            const float a02x = e0x + t2x, a02y = e0y + t2y;
            const float s02x = e0x - t2x, s02y = e0y - t2y;
            const float a13x = t1x + t3x, a13y = t1y + t3y;
            const float s13x = t1x - t3x, s13y = t1y - t3y;
            re[a0] = a02x + a13x;  im[a0] = a02y + a13y;
            re[a1] = s02x + s13y;  im[a1] = s02y - s13x;
            re[a2] = a02x - a13x;  im[a2] = a02y - a13y;
            re[a3] = s02x - s13y;  im[a3] = s02y + s13x;
        }
        __syncthreads();
    }
}

__global__ __launch_bounds__(256) void fft_pass1(const float* __restrict__ x,
                                                 float* __restrict__ out) {
    __shared__ float sre[64 * 65];
    __shared__ float sim[64 * 65];
    const int t  = threadIdx.x;
    const int pc = blockIdx.x & 7;
    const int n2 = (blockIdx.x >> 3) & 63;
    const int b  = blockIdx.x >> 9;
    const float* xb = x   + (size_t)b * SEQ * HID + pc * 128;
    float*       ob = out + (size_t)b * SEQ * HID + pc * 128;

    const int c  = t & 31;
    const int r0 = t >> 5;
    #pragma unroll
    for (int i = 0; i < 8; ++i) {
        const int r  = r0 + 8 * i;
        const float4 f = *(const float4*)(xb + (size_t)(n2 + 64 * r) * HID + 4 * c);
        const int rr = rev4_3(r);
        sre[rr * 65 + 2 * c]     = f.x;  sim[rr * 65 + 2 * c]     = f.y;
        sre[rr * 65 + 2 * c + 1] = f.z;  sim[rr * 65 + 2 * c + 1] = f.w;
    }
    __syncthreads();

    fft64_lds<4>(sre, sim, t & 63, 65, 4 * (t >> 6));

    const float tw = -1.5339807878856412e-3f;
    #pragma unroll
    for (int i = 0; i < 8; ++i) {
        const int k1 = r0 + 8 * i;
        float ws, wc;
        __sincosf(tw * (float)(n2 * k1), &ws, &wc);
        const float ar = sre[k1 * 65 + 2 * c],     ai = sim[k1 * 65 + 2 * c];
        const float br = sre[k1 * 65 + 2 * c + 1], bi = sim[k1 * 65 + 2 * c + 1];
        float4 f;
        f.x = ar * wc - ai * ws;  f.y = ar * ws + ai * wc;
        f.z = br * wc - bi * ws;  f.w = br * ws + bi * wc;
        *(float4*)(ob + (size_t)(64 * n2 + k1) * HID + 4 * c) = f;
    }
}

__global__ __launch_bounds__(256) void fft_pass2(float* out) {
    __shared__ float lds[8448];
    const int t   = threadIdx.x;
    const int b   = blockIdx.x >> 9;
    const int idx = blockIdx.x & 511;
    float* ob = out + (size_t)b * SEQ * HID;
    const float scale = 1.0f / 128.0f;

    if (idx < 496) {
        const int k1 = 1 + (idx >> 4);
        const int pc = idx & 15;
        float* are = lds;          float* aim = lds + 2112;
        float* bre = lds + 4224;   float* bim = lds + 6336;
        const int c  = t & 15;
        const int rg = t >> 4;
        #pragma unroll
        for (int i = 0; i < 4; ++i) {
            const int n2 = rg + 16 * i;
            const int rr = rev4_3(n2);
            const float4 fa = *(const float4*)(ob + (size_t)(64 * n2 + k1)      * HID + pc * 64 + 4 * c);
            const float4 fb = *(const float4*)(ob + (size_t)(64 * n2 + 64 - k1) * HID + pc * 64 + 4 * c);
            are[rr * 33 + 2 * c]     = fa.x;  aim[rr * 33 + 2 * c]     = fa.y;
            are[rr * 33 + 2 * c + 1] = fa.z;  aim[rr * 33 + 2 * c + 1] = fa.w;
            bre[rr * 33 + 2 * c]     = fb.x;  bim[rr * 33 + 2 * c]     = fb.y;
            bre[rr * 33 + 2 * c + 1] = fb.z;  bim[rr * 33 + 2 * c + 1] = fb.w;
        }
        __syncthreads();

        const int lane = t & 63;
        float* fre = lds + 4224 * (lane >> 5);
        fft64_lds<4>(fre, fre + 2112, lane & 31, 33, 4 * (t >> 6));

        #pragma unroll
        for (int i = 0; i < 4; ++i) {
            const int k2 = rg + 16 * i;
            const int q  = 63 - k2;
            float4 f, g;
            f.x = (are[k2 * 33 + 2 * c]     + bre[q * 33 + 2 * c])     * scale;
            f.y = (aim[k2 * 33 + 2 * c]     + bim[q * 33 + 2 * c])     * scale;
            f.z = (are[k2 * 33 + 2 * c + 1] + bre[q * 33 + 2 * c + 1]) * scale;
            f.w = (aim[k2 * 33 + 2 * c + 1] + bim[q * 33 + 2 * c + 1]) * scale;
            *(float4*)(ob + (size_t)(k1 + 64 * k2)      * HID + pc * 64 + 4 * c) = f;
            g.x = (bre[k2 * 33 + 2 * c]     + are[q * 33 + 2 * c])     * scale;
            g.y = (bim[k2 * 33 + 2 * c]     + aim[q * 33 + 2 * c])     * scale;
            g.z = (bre[k2 * 33 + 2 * c + 1] + are[q * 33 + 2 * c + 1]) * scale;
            g.w = (bim[k2 * 33 + 2 * c + 1] + aim[q * 33 + 2 * c + 1]) * scale;
            *(float4*)(ob + (size_t)(64 - k1 + 64 * k2) * HID + pc * 64 + 4 * c) = g;
        }
    } else {
        const int s  = idx - 496;
        const int k1 = (s >> 3) * 32;
        const int pc = s & 7;
        float* sre = lds;
        float* sim = lds + 4160;
        const int c  = t & 31;
        const int rg = t >> 5;
        #pragma unroll
        for (int i = 0; i < 8; ++i) {
            const int n2 = rg + 8 * i;
            const int rr = rev4_3(n2);
            const float4 f = *(const float4*)(ob + (size_t)(64 * n2 + k1) * HID + pc * 128 + 4 * c);
            sre[rr * 65 + 2 * c]     = f.x;  sim[rr * 65 + 2 * c]     = f.y;
            sre[rr * 65 + 2 * c + 1] = f.z;  sim[rr * 65 + 2 * c + 1] = f.w;
        }
        __syncthreads();

        fft64_lds<4>(sre, sim, t & 63, 65, 4 * (t >> 6));

        #pragma unroll
        for (int i = 0; i < 8; ++i) {
            const int k2 = rg + 8 * i;
            const int q  = (k1 == 0) ? ((64 - k2) & 63) : (63 - k2);
            float4 f;
            f.x = (sre[k2 * 65 + 2 * c]     + sre[q * 65 + 2 * c])     * scale;
            f.y = (sim[k2 * 65 + 2 * c]     + sim[q * 65 + 2 * c])     * scale;
            f.z = (sre[k2 * 65 + 2 * c + 1] + sre[q * 65 + 2 * c + 1]) * scale;
            f.w = (sim[k2 * 65 + 2 * c + 1] + sim[q * 65 + 2 * c + 1]) * scale;
            *(float4*)(ob + (size_t)(k1 + 64 * k2) * HID + pc * 128 + 4 * c) = f;
        }
    }
}

extern "C" void kernel_launch(void* const* d_in, const int* in_sizes, int n_in,
                              void* d_out, int out_size, void* d_ws, size_t ws_size,
                              hipStream_t stream) {
    const float* x = (const float*)d_in[0];
    float* out = (float*)d_out;
    const size_t need = (size_t)8 * SEQ * 512 * sizeof(__half2);   // 64 MiB
    if (ws_size >= need) {
        __half2* u = (__half2*)d_ws;
        fft_pass1_x2<<<dim3(8 * 64 * 4), dim3(512), 0, stream>>>(x, u);
        fft_pass2_x2<<<dim3(8 * 256), dim3(512), 0, stream>>>(u, out);
    } else {
        fft_pass1<<<dim3(8 * 64 * 8), dim3(256), 0, stream>>>(x, out);
        fft_pass2<<<dim3(8 * 512), dim3(256), 0, stream>>>(out);
    }
}